// Round 1
// baseline (26418.002 us; speedup 1.0000x reference)
//
#include <hip/hip_runtime.h>

// Problem constants (from reference): B=32, T=2048, D_IN=D_OUT=512, fp32.
constexpr int B = 32, T = 2048, D = 512;

// ---------------- Kernel 1: xw = x @ W + b, written in-place into d_out ----
// A is x viewed as [M=B*T][512] (row = b*T+t), C is d_out viewed the same way.
__global__ __launch_bounds__(256) void xw_gemm(
    const float* __restrict__ A, const float* __restrict__ W,
    const float* __restrict__ bias, float* __restrict__ C) {
  __shared__ float As[16][68];
  __shared__ float Bs[16][68];
  const int tid = threadIdx.x;
  const int M0 = blockIdx.y * 64, N0 = blockIdx.x * 64;
  const int tn = tid & 15, tm = tid >> 4;
  const int rA = tid >> 2, kA = (tid & 3) << 2;
  const int kB = tid >> 4, nB = (tid & 15) << 2;
  float acc[4][4] = {};
  for (int k0 = 0; k0 < 512; k0 += 16) {
    float4 a4 = *(const float4*)&A[(size_t)(M0 + rA) * 512 + k0 + kA];
    As[kA + 0][rA] = a4.x;
    As[kA + 1][rA] = a4.y;
    As[kA + 2][rA] = a4.z;
    As[kA + 3][rA] = a4.w;
    *(float4*)&Bs[kB][nB] = *(const float4*)&W[(size_t)(k0 + kB) * 512 + N0 + nB];
    __syncthreads();
#pragma unroll
    for (int k = 0; k < 16; ++k) {
      float a0 = As[k][tm * 4 + 0], a1 = As[k][tm * 4 + 1];
      float a2 = As[k][tm * 4 + 2], a3 = As[k][tm * 4 + 3];
      float b0 = Bs[k][tn * 4 + 0], b1 = Bs[k][tn * 4 + 1];
      float b2 = Bs[k][tn * 4 + 2], b3 = Bs[k][tn * 4 + 3];
      acc[0][0] += a0 * b0; acc[0][1] += a0 * b1; acc[0][2] += a0 * b2; acc[0][3] += a0 * b3;
      acc[1][0] += a1 * b0; acc[1][1] += a1 * b1; acc[1][2] += a1 * b2; acc[1][3] += a1 * b3;
      acc[2][0] += a2 * b0; acc[2][1] += a2 * b1; acc[2][2] += a2 * b2; acc[2][3] += a2 * b3;
      acc[3][0] += a3 * b0; acc[3][1] += a3 * b1; acc[3][2] += a3 * b2; acc[3][3] += a3 * b3;
    }
    __syncthreads();
  }
#pragma unroll
  for (int i = 0; i < 4; ++i) {
    const size_t row = (size_t)(M0 + tm * 4 + i);
    float4 v;
    v.x = acc[i][0] + bias[N0 + tn * 4 + 0];
    v.y = acc[i][1] + bias[N0 + tn * 4 + 1];
    v.z = acc[i][2] + bias[N0 + tn * 4 + 2];
    v.w = acc[i][3] + bias[N0 + tn * 4 + 3];
    *(float4*)&C[row * 512 + N0 + tn * 4] = v;
  }
}

// ---------------- Kernel 2: persistent recurrent scan ----------------------
// 64 blocks = 2 batch-groups (16 batches) x 32 col-groups (16 cols).
// W_rec column slice stays in LDS (swizzled) for all 2048 steps.
// h state lives in d_out itself: step t reads out[b][t-1][:] as h,
// reads out[b][t][:] as xw, overwrites with h_t (in-place).
constexpr int NBG = 2, NCG = 32;
constexpr int BPG = B / NBG;   // 16 batches per block
constexpr int CPG = D / NCG;   // 16 cols per block
constexpr int NBLK = NBG * NCG;  // 64
constexpr int NTHR = BPG * CPG;  // 256

__device__ inline void grid_barrier(unsigned* cnt, unsigned* gen) {
  __syncthreads();
  if (threadIdx.x == 0) {
    __threadfence();  // release: flush my out-writes to the coherence point
    unsigned g = __hip_atomic_load(gen, __ATOMIC_RELAXED, __HIP_MEMORY_SCOPE_AGENT);
    unsigned arrived =
        __hip_atomic_fetch_add(cnt, 1u, __ATOMIC_ACQ_REL, __HIP_MEMORY_SCOPE_AGENT);
    if (arrived == (unsigned)(NBLK - 1)) {
      __hip_atomic_store(cnt, 0u, __ATOMIC_RELAXED, __HIP_MEMORY_SCOPE_AGENT);
      __hip_atomic_store(gen, g + 1u, __ATOMIC_RELEASE, __HIP_MEMORY_SCOPE_AGENT);
    } else {
      while (__hip_atomic_load(gen, __ATOMIC_ACQUIRE, __HIP_MEMORY_SCOPE_AGENT) == g) {
        __builtin_amdgcn_s_sleep(1);
      }
    }
    __threadfence();  // acquire: invalidate so we see other XCDs' h writes
  }
  __syncthreads();
}

__global__ __launch_bounds__(NTHR) void rnn_scan(float* __restrict__ out,
                                                 const float* __restrict__ Wrec,
                                                 unsigned* cnt, unsigned* gen) {
  __shared__ float Wt_s[CPG][D];  // [c][k], k XOR-swizzled by (c&7)<<2
  __shared__ float h_s[BPG][D];   // [b][k], k XOR-swizzled by (b&7)<<2
  const int bg = blockIdx.x / NCG;
  const int cg = blockIdx.x % NCG;
  const int B0 = bg * BPG, C0 = cg * CPG;
  const int tid = threadIdx.x;

  // Load persistent W_rec slice: Wt_s[cl][k ^ swz] = Wrec[k][C0+cl]
  for (int idx = tid; idx < CPG * D; idx += NTHR) {
    int cl = idx & (CPG - 1);
    int k = idx >> 4;  // CPG == 16
    Wt_s[cl][k ^ ((cl & 7) << 2)] = Wrec[(size_t)k * D + C0 + cl];
  }

  const int b = tid >> 4;  // 0..15 local batch
  const int c = tid & 15;  // 0..15 local col
  const size_t rowBase = ((size_t)(B0 + b) * T) * D + C0 + c;
  const int hswz = (b & 7) << 2;
  const int wswz = (c & 7) << 2;

  // step 0: h0 = 0 -> out = tanh(xw)
  out[rowBase] = tanhf(out[rowBase]);

  for (int t = 1; t < T; ++t) {
    grid_barrier(cnt, gen);  // step t-1 fully written & visible
    // stage h = out[., t-1, :] into LDS (swizzled), 16 rows x 512
    for (int f4 = tid; f4 < BPG * (D / 4); f4 += NTHR) {
      int bl = f4 >> 7;  // D/4 == 128
      int k4 = f4 & 127;
      const float4 v =
          *(const float4*)&out[((size_t)(B0 + bl) * T + (t - 1)) * D + (k4 << 2)];
      *(float4*)&h_s[bl][(k4 << 2) ^ ((bl & 7) << 2)] = v;
    }
    __syncthreads();
    float acc = out[rowBase + (size_t)t * D];  // xw_t
    const float* hb = h_s[b];
    const float* wc = Wt_s[c];
#pragma unroll 4
    for (int k4 = 0; k4 < D / 4; ++k4) {
      float4 hv = *(const float4*)&hb[(k4 << 2) ^ hswz];
      float4 wv = *(const float4*)&wc[(k4 << 2) ^ wswz];
      acc += hv.x * wv.x + hv.y * wv.y + hv.z * wv.z + hv.w * wv.w;
    }
    out[rowBase + (size_t)t * D] = tanhf(acc);
  }
}

extern "C" void kernel_launch(void* const* d_in, const int* in_sizes, int n_in,
                              void* d_out, int out_size, void* d_ws, size_t ws_size,
                              hipStream_t stream) {
  const float* x = (const float*)d_in[0];
  const float* W = (const float*)d_in[1];
  const float* Wrec = (const float*)d_in[2];
  const float* bias = (const float*)d_in[3];
  float* out = (float*)d_out;

  // Kernel 1: xw + bias straight into d_out (row = b*T+t matches [B][T][D]).
  xw_gemm<<<dim3(D / 64, (B * T) / 64), 256, 0, stream>>>(x, W, bias, out);

  // Barrier state in d_ws (cnt @0, gen @64B) — reset every launch so replays
  // are deterministic.
  unsigned* cnt = (unsigned*)d_ws;
  unsigned* gen = (unsigned*)((char*)d_ws + 64);
  hipMemsetAsync(d_ws, 0, 256, stream);

  void* args[] = {(void*)&out, (void*)&Wrec, (void*)&cnt, (void*)&gen};
  hipLaunchCooperativeKernel(reinterpret_cast<void*>(rnn_scan), dim3(NBLK),
                             dim3(NTHR), args, 0, stream);
}

// Round 2
// 8387.375 us; speedup vs baseline: 3.1497x; 3.1497x over previous
//
#include <hip/hip_runtime.h>

// Problem constants (from reference): B=32, T=2048, D_IN=D_OUT=512, fp32.
constexpr int B = 32, T = 2048, D = 512;

// ---------------- Kernel 1: xw = x @ W + b, written in-place into d_out ----
__global__ __launch_bounds__(256) void xw_gemm(
    const float* __restrict__ A, const float* __restrict__ W,
    const float* __restrict__ bias, float* __restrict__ C) {
  __shared__ float As[16][68];
  __shared__ float Bs[16][68];
  const int tid = threadIdx.x;
  const int M0 = blockIdx.y * 64, N0 = blockIdx.x * 64;
  const int tn = tid & 15, tm = tid >> 4;
  const int rA = tid >> 2, kA = (tid & 3) << 2;
  const int kB = tid >> 4, nB = (tid & 15) << 2;
  float acc[4][4] = {};
  for (int k0 = 0; k0 < 512; k0 += 16) {
    float4 a4 = *(const float4*)&A[(size_t)(M0 + rA) * 512 + k0 + kA];
    As[kA + 0][rA] = a4.x;
    As[kA + 1][rA] = a4.y;
    As[kA + 2][rA] = a4.z;
    As[kA + 3][rA] = a4.w;
    *(float4*)&Bs[kB][nB] = *(const float4*)&W[(size_t)(k0 + kB) * 512 + N0 + nB];
    __syncthreads();
#pragma unroll
    for (int k = 0; k < 16; ++k) {
      float a0 = As[k][tm * 4 + 0], a1 = As[k][tm * 4 + 1];
      float a2 = As[k][tm * 4 + 2], a3 = As[k][tm * 4 + 3];
      float b0 = Bs[k][tn * 4 + 0], b1 = Bs[k][tn * 4 + 1];
      float b2 = Bs[k][tn * 4 + 2], b3 = Bs[k][tn * 4 + 3];
      acc[0][0] += a0 * b0; acc[0][1] += a0 * b1; acc[0][2] += a0 * b2; acc[0][3] += a0 * b3;
      acc[1][0] += a1 * b0; acc[1][1] += a1 * b1; acc[1][2] += a1 * b2; acc[1][3] += a1 * b3;
      acc[2][0] += a2 * b0; acc[2][1] += a2 * b1; acc[2][2] += a2 * b2; acc[2][3] += a2 * b3;
      acc[3][0] += a3 * b0; acc[3][1] += a3 * b1; acc[3][2] += a3 * b2; acc[3][3] += a3 * b3;
    }
    __syncthreads();
  }
#pragma unroll
  for (int i = 0; i < 4; ++i) {
    const size_t row = (size_t)(M0 + tm * 4 + i);
    float4 v;
    v.x = acc[i][0] + bias[N0 + tn * 4 + 0];
    v.y = acc[i][1] + bias[N0 + tn * 4 + 1];
    v.z = acc[i][2] + bias[N0 + tn * 4 + 2];
    v.w = acc[i][3] + bias[N0 + tn * 4 + 3];
    *(float4*)&C[row * 512 + N0 + tn * 4] = v;
  }
}

// ---------------- Kernel 2: clique-synced recurrent scan -------------------
// Grid = 8 batch-groups (bg) x 8 col-groups (cg) = 64 blocks x 512 threads.
// Block (bg,cg): batches [bg*4, +4), cols [cg*64, +64). Each thread (c, kq)
// holds W_rec[kq*64..+64)[C0+c] in 64 registers. Per step: consume clique's
// h_{t-1} slices from LLC (relaxed agent atomics, sc0sc1 -> no L2 cache ops),
// stage to LDS (k-octant XOR swizzle, conflict-free), 256 FMA into 4 acc
// chains, shfl_xor reduce over kq, tanh, publish slice + flag.
constexpr int NBG = 8, NCG = 8;
constexpr int BPB = B / NBG;    // 4 batches/block
constexpr int CPB = D / NCG;    // 64 cols/block
constexpr int NBLK = NBG * NCG; // 64
constexpr int NTHR = 512;       // 8 waves
constexpr int KPT = D / 8;      // 64 k per thread
constexpr int SLICE = BPB * CPB;  // 256 floats per published slice

__device__ __forceinline__ unsigned ld_flag(const unsigned* p) {
  return __hip_atomic_load(p, __ATOMIC_RELAXED, __HIP_MEMORY_SCOPE_AGENT);
}
__device__ __forceinline__ void st_flag(unsigned* p, unsigned v) {
  __hip_atomic_store(p, v, __ATOMIC_RELAXED, __HIP_MEMORY_SCOPE_AGENT);
}
__device__ __forceinline__ float ld_f(const float* p) {
  return __hip_atomic_load(p, __ATOMIC_RELAXED, __HIP_MEMORY_SCOPE_AGENT);
}
__device__ __forceinline__ void st_f(float* p, float v) {
  __hip_atomic_store(p, v, __ATOMIC_RELAXED, __HIP_MEMORY_SCOPE_AGENT);
}

__global__ __launch_bounds__(NTHR) void rnn_scan(
    float* __restrict__ out, const float* __restrict__ Wrec,
    float* __restrict__ xbuf, unsigned* __restrict__ flags) {
  __shared__ float h_s[BPB][D];  // staged h_{t-1}, k XOR-swizzled by (k>>6)<<2
  const int blk = blockIdx.x;
  const int bg = blk >> 3, cg = blk & 7;
  const int B0 = bg * BPB;
  const int C0 = cg * CPB;
  const int tid = threadIdx.x;
  const int c = tid >> 3;   // local col 0..63
  const int kq = tid & 7;   // k-octant
  const int k0 = kq * KPT;
  const int hswz = kq << 2;

  // W_rec slice into registers (one-time): w[jj] = Wrec[k0+4jj .. +3][C0+c]
  float4 w[16];
#pragma unroll
  for (int jj = 0; jj < 16; ++jj) {
    const float* p = &Wrec[(size_t)(k0 + 4 * jj) * D + C0 + c];
    w[jj].x = p[0 * D];
    w[jj].y = p[1 * D];
    w[jj].z = p[2 * D];
    w[jj].w = p[3 * D];
  }

  unsigned* myflag = flags + (size_t)blk * 32;          // 128B stride
  const unsigned* fl = flags + (size_t)bg * 8 * 32;     // clique flag base
  const int fi = tid & 7;
  const bool ownf = (fi == cg);

  // ---- step 0: h_0 = tanh(xw_0); publish into parity 0
  if (kq == 0) {
    float* dst = xbuf + ((size_t)(bg * 2 + 0) * NCG + cg) * SLICE;
#pragma unroll
    for (int b = 0; b < BPB; ++b) {
      const size_t o = ((size_t)(B0 + b) * T) * D + C0 + c;
      float h0 = tanhf(out[o]);
      out[o] = h0;
      st_f(&dst[b * CPB + c], h0);
    }
  }
  asm volatile("s_waitcnt vmcnt(0)" ::: "memory");
  __syncthreads();
  if (tid == 0) st_flag(myflag, 1u);

  for (int t = 1; t < T; ++t) {
    // prefetch xw_t (private region, plain cached loads; hidden by poll+compute)
    float xw0 = 0.f, xw1 = 0.f, xw2 = 0.f, xw3 = 0.f;
    if (kq == 0) {
      const size_t o = ((size_t)B0 * T + t) * D + C0 + c;
      xw0 = out[o];
      xw1 = out[o + (size_t)T * D];
      xw2 = out[o + 2 * (size_t)T * D];
      xw3 = out[o + 3 * (size_t)T * D];
    }
    // poll clique producers (own flag exempt)
    {
      const unsigned tgt = (unsigned)t;
      while (true) {
        unsigned v = ownf ? ~0u : ld_flag(&fl[(size_t)fi * 32]);
        if (__all(v >= tgt)) break;
      }
      asm volatile("" ::: "memory");
    }
    // stage h_{t-1}: 8 slices (2048 floats) -> LDS, 1 float4 per thread
    {
      const float* src =
          xbuf + ((size_t)(bg * 2 + ((t - 1) & 1)) * NCG) * SLICE;
      const int p = tid * 4;
      const int cg2 = p >> 8;       // producer col-group
      const int bb = (p >> 6) & 3;  // local batch
      const int cc = p & 63;        // col within slice
      const int k = cg2 * 64 + cc;  // global k index
      float4 hv;
      hv.x = ld_f(&src[p + 0]);
      hv.y = ld_f(&src[p + 1]);
      hv.z = ld_f(&src[p + 2]);
      hv.w = ld_f(&src[p + 3]);
      *(float4*)&h_s[bb][k ^ (cg2 << 2)] = hv;
    }
    __syncthreads();
    // compute: 4 batches x 64 k per thread, W in registers
    float a0 = 0.f, a1 = 0.f, a2 = 0.f, a3 = 0.f;
#pragma unroll
    for (int jj = 0; jj < 16; ++jj) {
      const int ko = (k0 + 4 * jj) ^ hswz;
      const float4 h0 = *(const float4*)&h_s[0][ko];
      const float4 h1 = *(const float4*)&h_s[1][ko];
      const float4 h2 = *(const float4*)&h_s[2][ko];
      const float4 h3 = *(const float4*)&h_s[3][ko];
      a0 += w[jj].x * h0.x + w[jj].y * h0.y + w[jj].z * h0.z + w[jj].w * h0.w;
      a1 += w[jj].x * h1.x + w[jj].y * h1.y + w[jj].z * h1.z + w[jj].w * h1.w;
      a2 += w[jj].x * h2.x + w[jj].y * h2.y + w[jj].z * h2.z + w[jj].w * h2.w;
      a3 += w[jj].x * h3.x + w[jj].y * h3.y + w[jj].z * h3.z + w[jj].w * h3.w;
    }
    // reduce over the 8 k-octants (lanes tid&7)
#pragma unroll
    for (int m = 1; m < 8; m <<= 1) {
      a0 += __shfl_xor(a0, m);
      a1 += __shfl_xor(a1, m);
      a2 += __shfl_xor(a2, m);
      a3 += __shfl_xor(a3, m);
    }
    // finalize + publish
    if (kq == 0) {
      float* dst = xbuf + ((size_t)(bg * 2 + (t & 1)) * NCG + cg) * SLICE;
      const size_t o = ((size_t)B0 * T + t) * D + C0 + c;
      float h;
      h = tanhf(a0 + xw0); out[o] = h;                       st_f(&dst[0 * CPB + c], h);
      h = tanhf(a1 + xw1); out[o + (size_t)T * D] = h;       st_f(&dst[1 * CPB + c], h);
      h = tanhf(a2 + xw2); out[o + 2 * (size_t)T * D] = h;   st_f(&dst[2 * CPB + c], h);
      h = tanhf(a3 + xw3); out[o + 3 * (size_t)T * D] = h;   st_f(&dst[3 * CPB + c], h);
    }
    asm volatile("s_waitcnt vmcnt(0)" ::: "memory");
    __syncthreads();  // all waves' publish stores drained
    if (tid == 0) st_flag(myflag, (unsigned)(t + 1));
  }
}

extern "C" void kernel_launch(void* const* d_in, const int* in_sizes, int n_in,
                              void* d_out, int out_size, void* d_ws, size_t ws_size,
                              hipStream_t stream) {
  const float* x = (const float*)d_in[0];
  const float* W = (const float*)d_in[1];
  const float* Wrec = (const float*)d_in[2];
  const float* bias = (const float*)d_in[3];
  float* out = (float*)d_out;

  // xw + bias straight into d_out (row = b*T+t matches [B][T][D]).
  xw_gemm<<<dim3(D / 64, (B * T) / 64), 256, 0, stream>>>(x, W, bias, out);

  // ws layout: flags [64 x 128B] at 0 (reset each launch); xbuf at +16KB
  // (8 bg x 2 parity x 8 cg x 256 floats = 128KB, fully rewritten before read).
  hipMemsetAsync(d_ws, 0, 8192, stream);
  unsigned* flags = (unsigned*)d_ws;
  float* xbuf = (float*)((char*)d_ws + 16384);

  void* args[] = {(void*)&out, (void*)&Wrec, (void*)&xbuf, (void*)&flags};
  hipLaunchCooperativeKernel(reinterpret_cast<void*>(rnn_scan), dim3(NBLK),
                             dim3(NTHR), args, 0, stream);
}

// Round 4
// 7457.948 us; speedup vs baseline: 3.5423x; 1.1246x over previous
//
#include <hip/hip_runtime.h>

// Problem constants (from reference): B=32, T=2048, D_IN=D_OUT=512, fp32.
constexpr int B = 32, T = 2048, D = 512;
constexpr size_t TD = (size_t)T * D;

// ---------------- Kernel 1: xw = x @ W + b, written in-place into d_out ----
__global__ __launch_bounds__(256) void xw_gemm(
    const float* __restrict__ A, const float* __restrict__ W,
    const float* __restrict__ bias, float* __restrict__ C) {
  __shared__ float As[16][68];
  __shared__ float Bs[16][68];
  const int tid = threadIdx.x;
  const int M0 = blockIdx.y * 64, N0 = blockIdx.x * 64;
  const int tn = tid & 15, tm = tid >> 4;
  const int rA = tid >> 2, kA = (tid & 3) << 2;
  const int kB = tid >> 4, nB = (tid & 15) << 2;
  float acc[4][4] = {};
  for (int k0 = 0; k0 < 512; k0 += 16) {
    float4 a4 = *(const float4*)&A[(size_t)(M0 + rA) * 512 + k0 + kA];
    As[kA + 0][rA] = a4.x;
    As[kA + 1][rA] = a4.y;
    As[kA + 2][rA] = a4.z;
    As[kA + 3][rA] = a4.w;
    *(float4*)&Bs[kB][nB] = *(const float4*)&W[(size_t)(k0 + kB) * 512 + N0 + nB];
    __syncthreads();
#pragma unroll
    for (int k = 0; k < 16; ++k) {
      float a0 = As[k][tm * 4 + 0], a1 = As[k][tm * 4 + 1];
      float a2 = As[k][tm * 4 + 2], a3 = As[k][tm * 4 + 3];
      float b0 = Bs[k][tn * 4 + 0], b1 = Bs[k][tn * 4 + 1];
      float b2 = Bs[k][tn * 4 + 2], b3 = Bs[k][tn * 4 + 3];
      acc[0][0] += a0 * b0; acc[0][1] += a0 * b1; acc[0][2] += a0 * b2; acc[0][3] += a0 * b3;
      acc[1][0] += a1 * b0; acc[1][1] += a1 * b1; acc[1][2] += a1 * b2; acc[1][3] += a1 * b3;
      acc[2][0] += a2 * b0; acc[2][1] += a2 * b1; acc[2][2] += a2 * b2; acc[2][3] += a2 * b3;
      acc[3][0] += a3 * b0; acc[3][1] += a3 * b1; acc[3][2] += a3 * b2; acc[3][3] += a3 * b3;
    }
    __syncthreads();
  }
#pragma unroll
  for (int i = 0; i < 4; ++i) {
    const size_t row = (size_t)(M0 + tm * 4 + i);
    float4 v;
    v.x = acc[i][0] + bias[N0 + tn * 4 + 0];
    v.y = acc[i][1] + bias[N0 + tn * 4 + 1];
    v.z = acc[i][2] + bias[N0 + tn * 4 + 2];
    v.w = acc[i][3] + bias[N0 + tn * 4 + 3];
    *(float4*)&C[row * 512 + N0 + tn * 4] = v;
  }
}

// ---------------- Kernel 2: clique scan with self-tagging h exchange -------
// 8 cliques (bg) x 8 blocks (cg), 512 threads. Block: 4 batches x 64 cols,
// W_rec slice in registers. Published h is band-encoded (h + off[t%4],
// off = {3,9,-3,-9}): every float is its own readiness flag -> no drain,
// no flag store, no flag poll. Transport: relaxed agent atomics (sc1, IC) —
// the exact proven round-2 codegen.
constexpr int NBG = 8, NCG = 8;
constexpr int BPB = 4;           // batches per clique
constexpr int CPB = 64;          // cols per block
constexpr int NBLK = 64, NTHR = 512;
constexpr int SLICE = BPB * CPB; // 256 floats, layout [c][b] (col-major)

__device__ __forceinline__ float ld_f(const float* p) {
  return __hip_atomic_load(p, __ATOMIC_RELAXED, __HIP_MEMORY_SCOPE_AGENT);
}
__device__ __forceinline__ void st_f(float* p, float v) {
  __hip_atomic_store(p, v, __ATOMIC_RELAXED, __HIP_MEMORY_SCOPE_AGENT);
}

__global__ __launch_bounds__(NTHR) void rnn_scan(float* __restrict__ out,
                                                 const float* __restrict__ Wrec,
                                                 float* __restrict__ xbuf) {
  __shared__ float h_s[2][BPB][D];  // parity-double-buffered, k XOR-swizzled
  const int blk = blockIdx.x;
  const int bg = blk >> 3, cg = blk & 7;
  const int B0 = bg * BPB, C0 = cg * CPB;
  const int tid = threadIdx.x;
  const int c = tid >> 3;   // local col 0..63
  const int kq = tid & 7;   // k-octant
  const int k0 = kq * 64;
  const int hswz = kq << 2;

  // W_rec slice into registers: w[jj] = Wrec[k0+4jj .. +3][C0+c]
  float4 w[16];
#pragma unroll
  for (int jj = 0; jj < 16; ++jj) {
    const float* p = &Wrec[(size_t)(k0 + 4 * jj) * D + C0 + c];
    w[jj].x = p[0 * D];
    w[jj].y = p[1 * D];
    w[jj].z = p[2 * D];
    w[jj].w = p[3 * D];
  }

  // clique exchange buffer: [parity][cg][slice(c*4+b)]
  float* cb = xbuf + (size_t)bg * 2 * NCG * SLICE;
  // staging assignment: thread covers 4 consecutive floats of the clique buf
  const int g = tid * 4;            // 0..2044
  const int cg2 = g >> 8;           // producer block 0..7
  const int c_loc = (g & 255) >> 2; // col within producer slice
  const int Cg = cg2 * 64 + c_loc;  // global k index of staged column
  const int ks = Cg ^ (cg2 << 2);   // swizzled LDS column
  const float OF[4] = {3.f, 9.f, -3.f, -9.f};

  // ---- step 0: h_0 = tanh(xw_0); publish band OF[0] into parity 0
  if (kq == 0) {
    float* dst = cb + (size_t)cg * SLICE + c * 4;
#pragma unroll
    for (int b = 0; b < BPB; ++b) {
      const size_t o = ((size_t)(B0 + b) * T) * D + C0 + c;
      float h0 = tanhf(out[o]);
      out[o] = h0;
      st_f(&dst[b], h0 + OF[0]);
    }
  }

  for (int t = 1; t < T; ++t) {
    const int pr = (t - 1) & 1;
    const float offR = OF[(t - 1) & 3];
    // prefetch xw_t (own write-once slots; plain cached loads, hidden by poll)
    float xw0 = 0.f, xw1 = 0.f, xw2 = 0.f, xw3 = 0.f;
    if (kq == 0) {
      const size_t o = ((size_t)B0 * T + t) * D + C0 + c;
      xw0 = out[o];
      xw1 = out[o + TD];
      xw2 = out[o + 2 * TD];
      xw3 = out[o + 3 * TD];
    }
    // poll own 4 floats until in-band (each float is its own flag)
    const float* src = cb + (size_t)pr * NCG * SLICE + g;
    float v0, v1, v2, v3;
    do {
      v0 = ld_f(src + 0);
      v1 = ld_f(src + 1);
      v2 = ld_f(src + 2);
      v3 = ld_f(src + 3);
    } while (!(fabsf(v0 - offR) < 1.5f && fabsf(v1 - offR) < 1.5f &&
               fabsf(v2 - offR) < 1.5f && fabsf(v3 - offR) < 1.5f));
    // decode + stage into LDS (4 batches of one column)
    h_s[pr][0][ks] = v0 - offR;
    h_s[pr][1][ks] = v1 - offR;
    h_s[pr][2][ks] = v2 - offR;
    h_s[pr][3][ks] = v3 - offR;
    __syncthreads();
    // compute: 4 batches x 64 k per thread, W in registers
    float a0 = 0.f, a1 = 0.f, a2 = 0.f, a3 = 0.f;
#pragma unroll
    for (int jj = 0; jj < 16; ++jj) {
      const int ko = (k0 + 4 * jj) ^ hswz;
      const float4 h0 = *(const float4*)&h_s[pr][0][ko];
      const float4 h1 = *(const float4*)&h_s[pr][1][ko];
      const float4 h2 = *(const float4*)&h_s[pr][2][ko];
      const float4 h3 = *(const float4*)&h_s[pr][3][ko];
      a0 += w[jj].x * h0.x + w[jj].y * h0.y + w[jj].z * h0.z + w[jj].w * h0.w;
      a1 += w[jj].x * h1.x + w[jj].y * h1.y + w[jj].z * h1.z + w[jj].w * h1.w;
      a2 += w[jj].x * h2.x + w[jj].y * h2.y + w[jj].z * h2.z + w[jj].w * h2.w;
      a3 += w[jj].x * h3.x + w[jj].y * h3.y + w[jj].z * h3.z + w[jj].w * h3.w;
    }
#pragma unroll
    for (int m = 1; m < 8; m <<= 1) {
      a0 += __shfl_xor(a0, m);
      a1 += __shfl_xor(a1, m);
      a2 += __shfl_xor(a2, m);
      a3 += __shfl_xor(a3, m);
    }
    // finalize: full-precision h_t to out[], band-encoded h_t to xbuf
    if (kq == 0) {
      const float offW = OF[t & 3];
      float* dst = cb + (size_t)(t & 1) * NCG * SLICE + (size_t)cg * SLICE + c * 4;
      const size_t o = ((size_t)B0 * T + t) * D + C0 + c;
      float h;
      h = tanhf(a0 + xw0); out[o] = h;          st_f(&dst[0], h + offW);
      h = tanhf(a1 + xw1); out[o + TD] = h;     st_f(&dst[1], h + offW);
      h = tanhf(a2 + xw2); out[o + 2 * TD] = h; st_f(&dst[2], h + offW);
      h = tanhf(a3 + xw3); out[o + 3 * TD] = h; st_f(&dst[3], h + offW);
    }
    // no drain, no flag: next step's poll self-gates on the data bands
  }
}

extern "C" void kernel_launch(void* const* d_in, const int* in_sizes, int n_in,
                              void* d_out, int out_size, void* d_ws, size_t ws_size,
                              hipStream_t stream) {
  const float* x = (const float*)d_in[0];
  const float* W = (const float*)d_in[1];
  const float* Wrec = (const float*)d_in[2];
  const float* bias = (const float*)d_in[3];
  float* out = (float*)d_out;

  // xw + bias straight into d_out (row = b*T+t matches [B][T][D]).
  xw_gemm<<<dim3(D / 64, (B * T) / 64), 256, 0, stream>>>(x, W, bias, out);

  // xbuf: 8 cliques x 2 parities x 8 blocks x 256 floats = 128 KB.
  // Zeroed every launch (zero is in no band) -> deterministic replays.
  hipMemsetAsync(d_ws, 0, (size_t)NBG * 2 * NCG * SLICE * sizeof(float), stream);
  float* xbuf = (float*)d_ws;

  void* args[] = {(void*)&out, (void*)&Wrec, (void*)&xbuf};
  hipLaunchCooperativeKernel(reinterpret_cast<void*>(rnn_scan), dim3(NBLK),
                             dim3(NTHR), args, 0, stream);
}

// Round 5
// 7154.569 us; speedup vs baseline: 3.6925x; 1.0424x over previous
//
#include <hip/hip_runtime.h>

// Problem constants (from reference): B=32, T=2048, D_IN=D_OUT=512, fp32.
constexpr int B = 32, T = 2048, D = 512;
constexpr size_t TD = (size_t)T * D;

// ---------------- Kernel 1: xw = x @ W + b, written in-place into d_out ----
__global__ __launch_bounds__(256) void xw_gemm(
    const float* __restrict__ A, const float* __restrict__ W,
    const float* __restrict__ bias, float* __restrict__ C) {
  __shared__ float As[16][68];
  __shared__ float Bs[16][68];
  const int tid = threadIdx.x;
  const int M0 = blockIdx.y * 64, N0 = blockIdx.x * 64;
  const int tn = tid & 15, tm = tid >> 4;
  const int rA = tid >> 2, kA = (tid & 3) << 2;
  const int kB = tid >> 4, nB = (tid & 15) << 2;
  float acc[4][4] = {};
  for (int k0 = 0; k0 < 512; k0 += 16) {
    float4 a4 = *(const float4*)&A[(size_t)(M0 + rA) * 512 + k0 + kA];
    As[kA + 0][rA] = a4.x;
    As[kA + 1][rA] = a4.y;
    As[kA + 2][rA] = a4.z;
    As[kA + 3][rA] = a4.w;
    *(float4*)&Bs[kB][nB] = *(const float4*)&W[(size_t)(k0 + kB) * 512 + N0 + nB];
    __syncthreads();
#pragma unroll
    for (int k = 0; k < 16; ++k) {
      float a0 = As[k][tm * 4 + 0], a1 = As[k][tm * 4 + 1];
      float a2 = As[k][tm * 4 + 2], a3 = As[k][tm * 4 + 3];
      float b0 = Bs[k][tn * 4 + 0], b1 = Bs[k][tn * 4 + 1];
      float b2 = Bs[k][tn * 4 + 2], b3 = Bs[k][tn * 4 + 3];
      acc[0][0] += a0 * b0; acc[0][1] += a0 * b1; acc[0][2] += a0 * b2; acc[0][3] += a0 * b3;
      acc[1][0] += a1 * b0; acc[1][1] += a1 * b1; acc[1][2] += a1 * b2; acc[1][3] += a1 * b3;
      acc[2][0] += a2 * b0; acc[2][1] += a2 * b1; acc[2][2] += a2 * b2; acc[2][3] += a2 * b3;
      acc[3][0] += a3 * b0; acc[3][1] += a3 * b1; acc[3][2] += a3 * b2; acc[3][3] += a3 * b3;
    }
    __syncthreads();
  }
#pragma unroll
  for (int i = 0; i < 4; ++i) {
    const size_t row = (size_t)(M0 + tm * 4 + i);
    float4 v;
    v.x = acc[i][0] + bias[N0 + tn * 4 + 0];
    v.y = acc[i][1] + bias[N0 + tn * 4 + 1];
    v.z = acc[i][2] + bias[N0 + tn * 4 + 2];
    v.w = acc[i][3] + bias[N0 + tn * 4 + 3];
    *(float4*)&C[row * 512 + N0 + tn * 4] = v;
  }
}

// ---------------- Kernel 2: staggered 2-batch, 4-block-clique scan ---------
// 64 blocks = 16 batch-pairs x 4 col-quarters, 512 threads.
// Block (pr,q): cols [128q,+128) of batches {2pr, 2pr+1}; W slice (512x128)
// in registers (128 VGPR/thread). Per round: phase A advances batch A one
// step, phase B advances batch B — batch A's IC publish latency hides under
// batch B's compute. h exchange: band-encoded floats (value==flag, round-4
// proven transport), 96 polling threads, early-issued loads.
constexpr int NBLK = 64, NTHR = 512;

__device__ __forceinline__ float ld_f(const float* p) {
  return __hip_atomic_load(p, __ATOMIC_RELAXED, __HIP_MEMORY_SCOPE_AGENT);
}
__device__ __forceinline__ void st_f(float* p, float v) {
  __hip_atomic_store(p, v, __ATOMIC_RELAXED, __HIP_MEMORY_SCOPE_AGENT);
}

__global__ __launch_bounds__(NTHR) void rnn_scan(float* __restrict__ out,
                                                 const float* __restrict__ Wrec,
                                                 float* __restrict__ xbuf) {
  // h_s[batch-in-pair][parity][chunk*132 + i]: 4 chunks of 128 + 4 pad floats
  __shared__ float h_s[2][2][4 * 132];
  const int blk = blockIdx.x;
  const int pr = blk >> 2;  // batch pair 0..15
  const int q = blk & 3;    // col quarter
  const int tid = threadIdx.x;
  const int w = tid >> 6, lane = tid & 63;
  const int kq = lane >> 4;              // k-quarter 0..3
  const int cl = (lane & 15) + 16 * w;   // local col 0..127
  const int k0 = kq * 128;
  const int C0 = q * 128;

  // W slice into registers: wreg[ki] = Wrec[(k0+ki)*D + C0+cl]
  float wreg[128];
  {
    const float* wp = Wrec + (size_t)k0 * D + C0 + cl;
#pragma unroll
    for (int ki = 0; ki < 128; ++ki) wreg[ki] = wp[(size_t)ki * D];
  }

  // xbuf per pair: [batch01][parity][quarter][128] = 2048 floats
  float* xb = xbuf + (size_t)pr * 2048;
  const float OF[4] = {3.f, 9.f, -3.f, -9.f};
  const bool fin = (kq == 0);       // 16 lanes/wave finalize col cl
  const bool poller = (tid < 96);   // 96 threads stage 3 foreign quarters
  int fq = 0, fi = 0;
  if (poller) {
    int g = tid >> 5;   // 0..2
    fi = tid & 31;      // float4 index within quarter
    fq = g + (g >= q);  // skip own quarter
  }

  const size_t rowA = ((size_t)(2 * pr) * T) * D + C0 + cl;      // + r*D
  const size_t rowB = ((size_t)(2 * pr + 1) * T) * D + C0 + cl;  // + r*D

  // ---- t = 0: h0 = tanh(xw_0); own h_s chunk for round 1 (parity 1);
  //      publish parity 0 band OF[0]
  if (fin) {
    float hA = tanhf(out[rowA]);
    float hB = tanhf(out[rowB]);
    out[rowA] = hA;
    out[rowB] = hB;
    h_s[0][1][q * 132 + cl] = hA;
    h_s[1][1][q * 132 + cl] = hB;
    st_f(&xb[(0 * 2 + 0) * 512 + q * 128 + cl], hA + OF[0]);
    st_f(&xb[(1 * 2 + 0) * 512 + q * 128 + cl], hB + OF[0]);
  }
  // early-issue poll loads for round 1 phase A (batch 0, parity 0)
  float eA0 = 0, eA1 = 0, eA2 = 0, eA3 = 0;
  float eB0 = 0, eB1 = 0, eB2 = 0, eB3 = 0;
  if (poller) {
    const float* p = xb + (0 * 2 + 0) * 512 + fq * 128 + fi * 4;
    eA0 = ld_f(p); eA1 = ld_f(p + 1); eA2 = ld_f(p + 2); eA3 = ld_f(p + 3);
  }

  for (int r = 1; r < T; ++r) {
    const int par = r & 1;         // h_s read parity & xbuf publish parity
    const int prev = (r - 1) & 1;  // xbuf consume parity
    const float offR = OF[(r - 1) & 3];
    const float offW = OF[r & 3];

    // ================= phase A (batch 2pr) =================
    float xwA = 0.f;
    if (fin) xwA = out[rowA + (size_t)r * D];  // prefetch, hides under poll/FMA
    if (poller) {
      const float* p = xb + (0 * 2 + prev) * 512 + fq * 128 + fi * 4;
      while (!(fabsf(eA0 - offR) < 1.5f && fabsf(eA1 - offR) < 1.5f &&
               fabsf(eA2 - offR) < 1.5f && fabsf(eA3 - offR) < 1.5f)) {
        eA0 = ld_f(p); eA1 = ld_f(p + 1); eA2 = ld_f(p + 2); eA3 = ld_f(p + 3);
      }
      float* hd = &h_s[0][par][fq * 132 + fi * 4];
      hd[0] = eA0 - offR; hd[1] = eA1 - offR; hd[2] = eA2 - offR; hd[3] = eA3 - offR;
      // early-issue for phase B: batch 1, parity prev
      const float* pB = xb + (1 * 2 + prev) * 512 + fq * 128 + fi * 4;
      eB0 = ld_f(pB); eB1 = ld_f(pB + 1); eB2 = ld_f(pB + 2); eB3 = ld_f(pB + 3);
    }
    __syncthreads();
    {
      const float* hp = &h_s[0][par][kq * 132];
      float acc = 0.f, acc2 = 0.f;
#pragma unroll
      for (int ki = 0; ki < 128; ki += 8) {
        float4 h0 = *(const float4*)&hp[ki];
        float4 h1 = *(const float4*)&hp[ki + 4];
        acc += wreg[ki + 0] * h0.x + wreg[ki + 1] * h0.y +
               wreg[ki + 2] * h0.z + wreg[ki + 3] * h0.w;
        acc2 += wreg[ki + 4] * h1.x + wreg[ki + 5] * h1.y +
                wreg[ki + 6] * h1.z + wreg[ki + 7] * h1.w;
      }
      acc += acc2;
      acc += __shfl_xor(acc, 16);
      acc += __shfl_xor(acc, 32);
      if (fin) {
        float h = tanhf(acc + xwA);
        out[rowA + (size_t)r * D] = h;
        st_f(&xb[(0 * 2 + par) * 512 + q * 128 + cl], h + offW);
        h_s[0][par ^ 1][q * 132 + cl] = h;  // own chunk for round r+1
      }
    }

    // ================= phase B (batch 2pr+1) =================
    float xwB = 0.f;
    if (fin) xwB = out[rowB + (size_t)r * D];
    if (poller) {
      const float* p = xb + (1 * 2 + prev) * 512 + fq * 128 + fi * 4;
      while (!(fabsf(eB0 - offR) < 1.5f && fabsf(eB1 - offR) < 1.5f &&
               fabsf(eB2 - offR) < 1.5f && fabsf(eB3 - offR) < 1.5f)) {
        eB0 = ld_f(p); eB1 = ld_f(p + 1); eB2 = ld_f(p + 2); eB3 = ld_f(p + 3);
      }
      float* hd = &h_s[1][par][fq * 132 + fi * 4];
      hd[0] = eB0 - offR; hd[1] = eB1 - offR; hd[2] = eB2 - offR; hd[3] = eB3 - offR;
      // early-issue for next round's phase A: batch 0, parity par
      const float* pA = xb + (0 * 2 + par) * 512 + fq * 128 + fi * 4;
      eA0 = ld_f(pA); eA1 = ld_f(pA + 1); eA2 = ld_f(pA + 2); eA3 = ld_f(pA + 3);
    }
    __syncthreads();
    {
      const float* hp = &h_s[1][par][kq * 132];
      float acc = 0.f, acc2 = 0.f;
#pragma unroll
      for (int ki = 0; ki < 128; ki += 8) {
        float4 h0 = *(const float4*)&hp[ki];
        float4 h1 = *(const float4*)&hp[ki + 4];
        acc += wreg[ki + 0] * h0.x + wreg[ki + 1] * h0.y +
               wreg[ki + 2] * h0.z + wreg[ki + 3] * h0.w;
        acc2 += wreg[ki + 4] * h1.x + wreg[ki + 5] * h1.y +
                wreg[ki + 6] * h1.z + wreg[ki + 7] * h1.w;
      }
      acc += acc2;
      acc += __shfl_xor(acc, 16);
      acc += __shfl_xor(acc, 32);
      if (fin) {
        float h = tanhf(acc + xwB);
        out[rowB + (size_t)r * D] = h;
        st_f(&xb[(1 * 2 + par) * 512 + q * 128 + cl], h + offW);
        h_s[1][par ^ 1][q * 132 + cl] = h;
      }
    }
  }
}

extern "C" void kernel_launch(void* const* d_in, const int* in_sizes, int n_in,
                              void* d_out, int out_size, void* d_ws, size_t ws_size,
                              hipStream_t stream) {
  const float* x = (const float*)d_in[0];
  const float* W = (const float*)d_in[1];
  const float* Wrec = (const float*)d_in[2];
  const float* bias = (const float*)d_in[3];
  float* out = (float*)d_out;

  // xw + bias straight into d_out (row = b*T+t matches [B][T][D]).
  xw_gemm<<<dim3(D / 64, (B * T) / 64), 256, 0, stream>>>(x, W, bias, out);

  // xbuf: 16 pairs x 2048 floats = 128 KB. Zeroed every launch (zero is in
  // no band) -> deterministic replays.
  hipMemsetAsync(d_ws, 0, (size_t)16 * 2048 * sizeof(float), stream);
  float* xbuf = (float*)d_ws;

  void* args[] = {(void*)&out, (void*)&Wrec, (void*)&xbuf};
  hipLaunchCooperativeKernel(reinterpret_cast<void*>(rnn_scan), dim3(NBLK),
                             dim3(NTHR), args, 0, stream);
}